// Round 7
// baseline (205.097 us; speedup 1.0000x reference)
//
#include <hip/hip_runtime.h>
#include <hip/hip_bf16.h>

#define NTOK 8192
#define DIM 2048
#define EXP 8
#define RK 64
#define OUTD 2048
#define SCALING (1.0f / 64.0f)
#define TTILE 32
#define MAXTILES (NTOK / TTILE) /* 256 */
#define JBINS 4                 /* step-B column split across blockIdx.y */
#define BK 128                  /* K-chunk (floats) staged per iteration */

typedef __attribute__((ext_vector_type(8))) short bf16x8;
typedef __attribute__((ext_vector_type(4))) short s16x4;
typedef __attribute__((ext_vector_type(4))) float f32x4;

__device__ __forceinline__ short f2bf(float f) {
    return __builtin_bit_cast(short, __float2bfloat16(f));
}

__device__ __forceinline__ bf16x8 load_cvt8(const float* __restrict__ p) {
    const float4 a = *(const float4*)(p);
    const float4 b = *(const float4*)(p + 4);
    bf16x8 r;
    r[0] = f2bf(a.x); r[1] = f2bf(a.y); r[2] = f2bf(a.z); r[3] = f2bf(a.w);
    r[4] = f2bf(b.x); r[5] = f2bf(b.y); r[6] = f2bf(b.z); r[7] = f2bf(b.w);
    return r;
}

__global__ void init_counts(int* __restrict__ counts) {
    if (threadIdx.x < EXP) counts[threadIdx.x] = 0;
}

// Router v2: 1 token per WAVE (was 4) -> 8192 waves on 2048 blocks, 32
// waves/CU. Per-token arithmetic is bit-identical to the R1/R5/R6-proven
// router: same c = lane + 64*i traversal, same f64 per-lane partial order,
// same 64-lane butterfly, same f64 bias/argmax/softmax tail, same direct
// bucket atomic write. Only the wave->token mapping changed.
__global__ __launch_bounds__(256) void router_kernel(
    const float* __restrict__ X, const float* __restrict__ Wr,
    const float* __restrict__ br, int* __restrict__ counts,
    float* __restrict__ wts, int* __restrict__ bucket) {
    const int n = (blockIdx.x * 256 + threadIdx.x) >> 6;  // token id 0..8191
    const int lane = threadIdx.x & 63;

    double acc[EXP];
#pragma unroll
    for (int e = 0; e < EXP; ++e) acc[e] = 0.0;

    const float4* X4 = (const float4*)X + (size_t)n * 512;
    const float4* W4 = (const float4*)Wr;
#pragma unroll
    for (int i = 0; i < 8; ++i) {
        const int c = lane + 64 * i;  // float4 column, 0..511
        const float4 xv = X4[c];
#pragma unroll
        for (int e = 0; e < EXP; ++e) {
            const float4 wv = W4[e * 512 + c];
            acc[e] += (double)xv.x * wv.x + (double)xv.y * wv.y +
                      (double)xv.z * wv.z + (double)xv.w * wv.w;
        }
    }

    // full-wave butterfly reduce (all lanes end with the sum)
#pragma unroll
    for (int e = 0; e < EXP; ++e) {
        double v = acc[e];
#pragma unroll
        for (int off = 32; off >= 1; off >>= 1) v += __shfl_xor(v, off, 64);
        acc[e] = v;
    }

    if (lane == 0) {
        double lg[EXP];
#pragma unroll
        for (int e = 0; e < EXP; ++e) lg[e] = acc[e] + (double)br[e];
        double m = lg[0];
        int bi = 0;
#pragma unroll
        for (int e = 1; e < EXP; ++e)
            if (lg[e] > m) { m = lg[e]; bi = e; }
        float s = 0.f;
#pragma unroll
        for (int e = 0; e < EXP; ++e) s += __expf((float)(lg[e] - m));
        wts[n] = 1.0f / s;  // max softmax prob
        const int slot = atomicAdd(&counts[bi], 1);
        bucket[bi * NTOK + slot] = n;
    }
}

// Grouped LoRA (R6-verbatim). One block per (expert, 32-token tile, column
// quarter). Step A stages X/A chunks into LDS with coalesced loads; step B
// reads B rows directly (16 contiguous 128B segments per instr).
__global__ __launch_bounds__(256) void moe_lora_kernel(
    const float* __restrict__ X, const float* __restrict__ A,
    const float* __restrict__ B, const int* __restrict__ counts,
    const float* __restrict__ wts, const int* __restrict__ bucket,
    float* __restrict__ out) {
    const int e = blockIdx.x >> 8;       // MAXTILES == 256
    const int tile = blockIdx.x & 255;
    const int jbin = blockIdx.y;         // 0..JBINS-1, column quarter
    const int cnt = counts[e];
    const int base = tile * TTILE;
    if (base >= cnt) return;
    const int nt = min(TTILE, cnt - base);

    __shared__ int toks[TTILE];
    __shared__ float wt_s[TTILE];
    __shared__ short Xs[TTILE * BK];  // 32 rows x 128 bf16, swizzled, 8 KB
    __shared__ short As[RK * BK];     // 64 rows x 128 bf16, swizzled, 16 KB
    __shared__ short Hs[TTILE * RK];  // bf16 h, XOR-swizzled, 4 KB

    const int tid = threadIdx.x;
    if (tid < TTILE) {
        const int tk = bucket[e * NTOK + base + min(tid, nt - 1)];
        toks[tid] = tk;
        wt_s[tid] = wts[tk];
    }
    __syncthreads();

    const int wv = tid >> 6;     // wave 0..3
    const int lane = tid & 63;
    const int lrow = lane & 15;  // M/N index within fragment
    const int lk = lane >> 4;    // k-block 0..3

    // ---- Step A: h[32][64] = Xtile @ A[e]^T, LDS-staged ----
    const float* Ae = A + (size_t)e * RK * DIM;
    const int scol = (tid & 31) * 4;   // f32 col within chunk (0..124)
    const int srow = tid >> 5;         // 0..7

    f32x4 hacc0 = {0.f, 0.f, 0.f, 0.f};
    f32x4 hacc1 = {0.f, 0.f, 0.f, 0.f};

    for (int ch = 0; ch < DIM / BK; ++ch) {
        const int k0 = ch * BK;
        __syncthreads();  // previous chunk's ds_reads complete
        // stage X: 4 instrs, 8 rows each, 512B contiguous per row
#pragma unroll
        for (int i = 0; i < 4; ++i) {
            const int row = i * 8 + srow;
            const float4 xv =
                *(const float4*)(X + (size_t)toks[row] * DIM + k0 + scol);
            s16x4 h4 = {f2bf(xv.x), f2bf(xv.y), f2bf(xv.z), f2bf(xv.w)};
            *(s16x4*)((char*)Xs + ((row * 256 + scol * 2) ^ ((row & 7) << 4))) = h4;
        }
        // stage A: 8 instrs, rows 0..63
#pragma unroll
        for (int i = 0; i < 8; ++i) {
            const int row = i * 8 + srow;
            const float4 av =
                *(const float4*)(Ae + (size_t)row * DIM + k0 + scol);
            s16x4 h4 = {f2bf(av.x), f2bf(av.y), f2bf(av.z), f2bf(av.w)};
            *(s16x4*)((char*)As + ((row * 256 + scol * 2) ^ ((row & 7) << 4))) = h4;
        }
        __syncthreads();
        // 4 MFMA K-steps from LDS
#pragma unroll
        for (int kk = 0; kk < 4; ++kk) {
            const int cb = kk * 64 + lk * 16;  // byte col within row
            const bf16x8 xf0 = *(const bf16x8*)((char*)Xs +
                ((lrow * 256 + cb) ^ ((lrow & 7) << 4)));
            const bf16x8 xf1 = *(const bf16x8*)((char*)Xs +
                (((16 + lrow) * 256 + cb) ^ ((lrow & 7) << 4)));
            const int ar = wv * 16 + lrow;
            const bf16x8 af = *(const bf16x8*)((char*)As +
                ((ar * 256 + cb) ^ ((ar & 7) << 4)));
            hacc0 = __builtin_amdgcn_mfma_f32_16x16x32_bf16(xf0, af, hacc0, 0, 0, 0);
            hacc1 = __builtin_amdgcn_mfma_f32_16x16x32_bf16(xf1, af, hacc1, 0, 0, 0);
        }
    }

    // write h to LDS as bf16, XOR-swizzled rows of 64 bf16 (128 B)
#pragma unroll
    for (int m = 0; m < 2; ++m) {
#pragma unroll
        for (int reg = 0; reg < 4; ++reg) {
            const int t = m * 16 + lk * 4 + reg;
            const int r = wv * 16 + lrow;
            const int byte = ((t * RK + r) * 2) ^ ((t & 7) << 4);
            const float hv = (m == 0) ? hacc0[reg] : hacc1[reg];
            *(short*)((char*)Hs + byte) = f2bf(hv);
        }
    }
    __syncthreads();

    // ---- Step B: y[32][512-chunk] = h @ B[e]^T, scale, scatter ----
    bf16x8 hf[2][2];
#pragma unroll
    for (int m = 0; m < 2; ++m)
#pragma unroll
        for (int k2 = 0; k2 < 2; ++k2) {
            const int t = m * 16 + lrow;
            const int r = k2 * 32 + lk * 8;
            const int byte = ((t * RK + r) * 2) ^ ((t & 7) << 4);
            hf[m][k2] = *(const bf16x8*)((char*)Hs + byte);
        }

    float scl[2][4];
    int trow[2][4];
    bool tok_ok[2][4];
#pragma unroll
    for (int m = 0; m < 2; ++m)
#pragma unroll
        for (int reg = 0; reg < 4; ++reg) {
            const int t = m * 16 + lk * 4 + reg;
            scl[m][reg] = SCALING * wt_s[t];
            trow[m][reg] = toks[t];
            tok_ok[m][reg] = (t < nt);
        }

    const float* Be = B + (size_t)e * OUTD * RK;
    const int j0 = jbin * (OUTD / 64 / JBINS);  // 8 j's per bin
    for (int j = j0; j < j0 + OUTD / 64 / JBINS; ++j) {
        const int n = (wv + 4 * j) * 16;
        f32x4 yacc0 = {0.f, 0.f, 0.f, 0.f};
        f32x4 yacc1 = {0.f, 0.f, 0.f, 0.f};
#pragma unroll
        for (int k2 = 0; k2 < 2; ++k2) {
            const bf16x8 bf =
                load_cvt8(Be + (size_t)(n + lrow) * RK + k2 * 32 + lk * 8);
            yacc0 = __builtin_amdgcn_mfma_f32_16x16x32_bf16(hf[0][k2], bf, yacc0, 0, 0, 0);
            yacc1 = __builtin_amdgcn_mfma_f32_16x16x32_bf16(hf[1][k2], bf, yacc1, 0, 0, 0);
        }
#pragma unroll
        for (int m = 0; m < 2; ++m) {
#pragma unroll
            for (int reg = 0; reg < 4; ++reg) {
                if (tok_ok[m][reg]) {
                    const float y = ((m == 0) ? yacc0[reg] : yacc1[reg]) * scl[m][reg];
                    out[(size_t)trow[m][reg] * OUTD + n + lrow] = y;
                }
            }
        }
    }
}

extern "C" void kernel_launch(void* const* d_in, const int* in_sizes, int n_in,
                              void* d_out, int out_size, void* d_ws, size_t ws_size,
                              hipStream_t stream) {
    const float* X = (const float*)d_in[0];
    const float* A = (const float*)d_in[1];
    const float* B = (const float*)d_in[2];
    const float* Wr = (const float*)d_in[3];
    const float* br = (const float*)d_in[4];
    float* out = (float*)d_out;

    int* counts = (int*)d_ws;
    float* wts = (float*)((char*)d_ws + 64);
    int* bucket = (int*)((char*)d_ws + 64 + NTOK * 4);

    init_counts<<<1, 64, 0, stream>>>(counts);
    router_kernel<<<NTOK * 64 / 256, 256, 0, stream>>>(X, Wr, br, counts, wts, bucket);
    dim3 grid(EXP * MAXTILES, JBINS);
    moe_lora_kernel<<<grid, 256, 0, stream>>>(X, A, B, counts, wts, bucket, out);
}

// Round 8
// 137.932 us; speedup vs baseline: 1.4869x; 1.4869x over previous
//
#include <hip/hip_runtime.h>
#include <hip/hip_bf16.h>

#define NTOK 8192
#define DIM 2048
#define EXP 8
#define RK 64
#define OUTD 2048
#define SCALING (1.0f / 64.0f)
#define TTILE 64
#define MAXTILES (NTOK / TTILE) /* 128 */
#define JBINS 2                 /* step-B column split across blockIdx.y */
#define BK 128                  /* K-chunk (floats) staged per iteration */
#define MT (TTILE / 16)         /* 4 m-fragments per wave */

typedef __attribute__((ext_vector_type(8))) short bf16x8;
typedef __attribute__((ext_vector_type(4))) short s16x4;
typedef __attribute__((ext_vector_type(4))) float f32x4;

__device__ __forceinline__ short f2bf(float f) {
    return __builtin_bit_cast(short, __float2bfloat16(f));
}

__device__ __forceinline__ bf16x8 load_cvt8(const float* __restrict__ p) {
    const float4 a = *(const float4*)(p);
    const float4 b = *(const float4*)(p + 4);
    bf16x8 r;
    r[0] = f2bf(a.x); r[1] = f2bf(a.y); r[2] = f2bf(a.z); r[3] = f2bf(a.w);
    r[4] = f2bf(b.x); r[5] = f2bf(b.y); r[6] = f2bf(b.z); r[7] = f2bf(b.w);
    return r;
}

__global__ void init_counts(int* __restrict__ counts) {
    if (threadIdx.x < EXP) counts[threadIdx.x] = 0;
}

// Router (R1/R5/R6-verbatim, proven 55 us / bit-exact): 4 tokens per wave —
// the Wr loads amortize over 4 tokens (24 load-instrs/token). R7's 1-tok/wave
// variant tripled load instrs and regressed 2.2x: this kernel is bound by
// L1-missing load instructions, NOT occupancy.
__global__ __launch_bounds__(256) void router_kernel(
    const float* __restrict__ X, const float* __restrict__ Wr,
    const float* __restrict__ br, int* __restrict__ counts,
    float* __restrict__ wts, int* __restrict__ bucket) {
    const int wave = (blockIdx.x * 256 + threadIdx.x) >> 6;
    const int lane = threadIdx.x & 63;
    const int t0 = wave * 4;
    if (t0 >= NTOK) return;

    double acc[4][EXP];
#pragma unroll
    for (int t = 0; t < 4; ++t)
#pragma unroll
        for (int e = 0; e < EXP; ++e) acc[t][e] = 0.0;

    const float4* X4 = (const float4*)X;
    const float4* W4 = (const float4*)Wr;
#pragma unroll
    for (int i = 0; i < 8; ++i) {
        const int c = lane + 64 * i;  // float4 column, 0..511
        float4 xv0 = X4[(size_t)(t0 + 0) * 512 + c];
        float4 xv1 = X4[(size_t)(t0 + 1) * 512 + c];
        float4 xv2 = X4[(size_t)(t0 + 2) * 512 + c];
        float4 xv3 = X4[(size_t)(t0 + 3) * 512 + c];
#pragma unroll
        for (int e = 0; e < EXP; ++e) {
            const float4 wv = W4[e * 512 + c];
            acc[0][e] += (double)xv0.x * wv.x + (double)xv0.y * wv.y +
                         (double)xv0.z * wv.z + (double)xv0.w * wv.w;
            acc[1][e] += (double)xv1.x * wv.x + (double)xv1.y * wv.y +
                         (double)xv1.z * wv.z + (double)xv1.w * wv.w;
            acc[2][e] += (double)xv2.x * wv.x + (double)xv2.y * wv.y +
                         (double)xv2.z * wv.z + (double)xv2.w * wv.w;
            acc[3][e] += (double)xv3.x * wv.x + (double)xv3.y * wv.y +
                         (double)xv3.z * wv.z + (double)xv3.w * wv.w;
        }
    }

#pragma unroll
    for (int t = 0; t < 4; ++t)
#pragma unroll
        for (int e = 0; e < EXP; ++e) {
            double v = acc[t][e];
#pragma unroll
            for (int off = 32; off >= 1; off >>= 1) v += __shfl_xor(v, off, 64);
            acc[t][e] = v;
        }

#pragma unroll
    for (int t = 0; t < 4; ++t) {
        if (lane == t) {
            double lg[EXP];
#pragma unroll
            for (int e = 0; e < EXP; ++e) lg[e] = acc[t][e] + (double)br[e];
            double m = lg[0];
            int bi = 0;
#pragma unroll
            for (int e = 1; e < EXP; ++e)
                if (lg[e] > m) { m = lg[e]; bi = e; }
            float s = 0.f;
#pragma unroll
            for (int e = 0; e < EXP; ++e) s += __expf((float)(lg[e] - m));
            const int n = t0 + t;
            wts[n] = 1.0f / s;  // max softmax prob
            const int slot = atomicAdd(&counts[bi], 1);
            bucket[bi * NTOK + slot] = n;
        }
    }
}

// Grouped LoRA. R6 structure with TTILE 32->64, JBINS 4->2: halves the
// redundant A/X re-staging traffic (R6 was ~950 MB logical for a 165 MB
// problem, L3-service-bound at ~10 TB/s). Per-token K accumulation order
// (ch asc, kk within ch, k2 in step B) is unchanged -> bit-identical output.
__global__ __launch_bounds__(256) void moe_lora_kernel(
    const float* __restrict__ X, const float* __restrict__ A,
    const float* __restrict__ B, const int* __restrict__ counts,
    const float* __restrict__ wts, const int* __restrict__ bucket,
    float* __restrict__ out) {
    const int e = blockIdx.x >> 7;       // MAXTILES == 128
    const int tile = blockIdx.x & 127;
    const int jbin = blockIdx.y;         // 0..JBINS-1, column half
    const int cnt = counts[e];
    const int base = tile * TTILE;
    if (base >= cnt) return;
    const int nt = min(TTILE, cnt - base);

    __shared__ int toks[TTILE];
    __shared__ float wt_s[TTILE];
    __shared__ short Xs[TTILE * BK];  // 64 rows x 128 bf16, swizzled, 16 KB
    __shared__ short As[RK * BK];     // 64 rows x 128 bf16, swizzled, 16 KB
    __shared__ short Hs[TTILE * RK];  // 64 x 64 bf16 h, XOR-swizzled, 8 KB

    const int tid = threadIdx.x;
    if (tid < TTILE) {
        const int tk = bucket[e * NTOK + base + min(tid, nt - 1)];
        toks[tid] = tk;
        wt_s[tid] = wts[tk];
    }
    __syncthreads();

    const int wv = tid >> 6;     // wave 0..3
    const int lane = tid & 63;
    const int lrow = lane & 15;  // M/N index within fragment
    const int lk = lane >> 4;    // k-block 0..3

    // ---- Step A: h[64][64] = Xtile @ A[e]^T, LDS-staged ----
    const float* Ae = A + (size_t)e * RK * DIM;
    const int scol = (tid & 31) * 4;   // f32 col within chunk (0..124)
    const int srow = tid >> 5;         // 0..7

    f32x4 hacc[MT];
#pragma unroll
    for (int m = 0; m < MT; ++m) hacc[m] = (f32x4){0.f, 0.f, 0.f, 0.f};

    for (int ch = 0; ch < DIM / BK; ++ch) {
        const int k0 = ch * BK;
        __syncthreads();  // previous chunk's ds_reads complete
        // stage X: 8 instrs, 8 rows each, 512B contiguous per row
#pragma unroll
        for (int i = 0; i < 8; ++i) {
            const int row = i * 8 + srow;
            const float4 xv =
                *(const float4*)(X + (size_t)toks[row] * DIM + k0 + scol);
            s16x4 h4 = {f2bf(xv.x), f2bf(xv.y), f2bf(xv.z), f2bf(xv.w)};
            *(s16x4*)((char*)Xs + ((row * 256 + scol * 2) ^ ((row & 7) << 4))) = h4;
        }
        // stage A: 8 instrs, rows 0..63
#pragma unroll
        for (int i = 0; i < 8; ++i) {
            const int row = i * 8 + srow;
            const float4 av =
                *(const float4*)(Ae + (size_t)row * DIM + k0 + scol);
            s16x4 h4 = {f2bf(av.x), f2bf(av.y), f2bf(av.z), f2bf(av.w)};
            *(s16x4*)((char*)As + ((row * 256 + scol * 2) ^ ((row & 7) << 4))) = h4;
        }
        __syncthreads();
        // 4 MFMA K-steps from LDS, 4 m-fragments each
#pragma unroll
        for (int kk = 0; kk < 4; ++kk) {
            const int cb = kk * 64 + lk * 16;  // byte col within row
            const int ar = wv * 16 + lrow;
            const bf16x8 af = *(const bf16x8*)((char*)As +
                ((ar * 256 + cb) ^ ((ar & 7) << 4)));
#pragma unroll
            for (int m = 0; m < MT; ++m) {
                const int xr = m * 16 + lrow;
                const bf16x8 xf = *(const bf16x8*)((char*)Xs +
                    ((xr * 256 + cb) ^ ((xr & 7) << 4)));
                hacc[m] = __builtin_amdgcn_mfma_f32_16x16x32_bf16(xf, af, hacc[m], 0, 0, 0);
            }
        }
    }

    // write h to LDS as bf16, XOR-swizzled rows of 64 bf16 (128 B)
#pragma unroll
    for (int m = 0; m < MT; ++m) {
#pragma unroll
        for (int reg = 0; reg < 4; ++reg) {
            const int t = m * 16 + lk * 4 + reg;
            const int r = wv * 16 + lrow;
            const int byte = ((t * RK + r) * 2) ^ ((t & 7) << 4);
            *(short*)((char*)Hs + byte) = f2bf(hacc[m][reg]);
        }
    }
    __syncthreads();

    // ---- Step B: y[64][1024-chunk] = h @ B[e]^T, scale, scatter ----
    bf16x8 hf[MT][2];
#pragma unroll
    for (int m = 0; m < MT; ++m)
#pragma unroll
        for (int k2 = 0; k2 < 2; ++k2) {
            const int t = m * 16 + lrow;
            const int r = k2 * 32 + lk * 8;
            const int byte = ((t * RK + r) * 2) ^ ((t & 7) << 4);
            hf[m][k2] = *(const bf16x8*)((char*)Hs + byte);
        }

    float scl[MT][4];
    int trow[MT][4];
    bool tok_ok[MT][4];
#pragma unroll
    for (int m = 0; m < MT; ++m)
#pragma unroll
        for (int reg = 0; reg < 4; ++reg) {
            const int t = m * 16 + lk * 4 + reg;
            scl[m][reg] = SCALING * wt_s[t];
            trow[m][reg] = toks[t];
            tok_ok[m][reg] = (t < nt);
        }

    const float* Be = B + (size_t)e * OUTD * RK;
    const int j0 = jbin * (OUTD / 64 / JBINS);  // 16 j's per bin
    for (int j = j0; j < j0 + OUTD / 64 / JBINS; ++j) {
        const int n = (wv + 4 * j) * 16;
        f32x4 yacc[MT];
#pragma unroll
        for (int m = 0; m < MT; ++m) yacc[m] = (f32x4){0.f, 0.f, 0.f, 0.f};
#pragma unroll
        for (int k2 = 0; k2 < 2; ++k2) {
            const bf16x8 bf =
                load_cvt8(Be + (size_t)(n + lrow) * RK + k2 * 32 + lk * 8);
#pragma unroll
            for (int m = 0; m < MT; ++m)
                yacc[m] = __builtin_amdgcn_mfma_f32_16x16x32_bf16(hf[m][k2], bf, yacc[m], 0, 0, 0);
        }
#pragma unroll
        for (int m = 0; m < MT; ++m) {
#pragma unroll
            for (int reg = 0; reg < 4; ++reg) {
                if (tok_ok[m][reg]) {
                    const float y = yacc[m][reg] * scl[m][reg];
                    out[(size_t)trow[m][reg] * OUTD + n + lrow] = y;
                }
            }
        }
    }
}

extern "C" void kernel_launch(void* const* d_in, const int* in_sizes, int n_in,
                              void* d_out, int out_size, void* d_ws, size_t ws_size,
                              hipStream_t stream) {
    const float* X = (const float*)d_in[0];
    const float* A = (const float*)d_in[1];
    const float* B = (const float*)d_in[2];
    const float* Wr = (const float*)d_in[3];
    const float* br = (const float*)d_in[4];
    float* out = (float*)d_out;

    int* counts = (int*)d_ws;
    float* wts = (float*)((char*)d_ws + 64);
    int* bucket = (int*)((char*)d_ws + 64 + NTOK * 4);

    init_counts<<<1, 64, 0, stream>>>(counts);
    router_kernel<<<NTOK / 16, 256, 0, stream>>>(X, Wr, br, counts, wts, bucket);
    dim3 grid(EXP * MAXTILES, JBINS);
    moe_lora_kernel<<<grid, 256, 0, stream>>>(X, A, B, counts, wts, bucket, out);
}

// Round 9
// 137.253 us; speedup vs baseline: 1.4943x; 1.0049x over previous
//
#include <hip/hip_runtime.h>
#include <hip/hip_bf16.h>

#define NTOK 8192
#define DIM 2048
#define EXP 8
#define RK 64
#define OUTD 2048
#define SCALING (1.0f / 64.0f)
#define TTILE 64
#define MAXTILES (NTOK / TTILE) /* 128 */
#define JBINS 2                 /* step-B column split across blockIdx.y */
#define BK 128                  /* K-chunk (floats) staged per iteration */
#define MT (TTILE / 16)         /* 4 m-fragments per wave */

typedef __attribute__((ext_vector_type(8))) short bf16x8;
typedef __attribute__((ext_vector_type(4))) short s16x4;
typedef __attribute__((ext_vector_type(4))) float f32x4;

__device__ __forceinline__ short f2bf(float f) {
    return __builtin_bit_cast(short, __float2bfloat16(f));
}

__device__ __forceinline__ bf16x8 load_cvt8(const float* __restrict__ p) {
    const float4 a = *(const float4*)(p);
    const float4 b = *(const float4*)(p + 4);
    bf16x8 r;
    r[0] = f2bf(a.x); r[1] = f2bf(a.y); r[2] = f2bf(a.z); r[3] = f2bf(a.w);
    r[4] = f2bf(b.x); r[5] = f2bf(b.y); r[6] = f2bf(b.z); r[7] = f2bf(b.w);
    return r;
}

__global__ void init_counts(int* __restrict__ counts) {
    if (threadIdx.x < EXP) counts[threadIdx.x] = 0;
}

// Router v3: 8 tokens per wave, ONE wave per block, __launch_bounds__(64,1)
// so the 128-VGPR f64 accumulator array stays in registers (R6's 4-tok/256thr
// variant reported VGPR_Count=56 < the 64 VGPRs acc needs -> scratch spills =
// the 55us). Per-token arithmetic is bit-identical to the proven router:
// same c = lane + 64*i column traversal, same f64 per-lane FMA order, same
// 64-lane butterfly, same f64 bias/argmax/softmax tail, same bucket write.
__global__ __launch_bounds__(64, 1) void router_kernel(
    const float* __restrict__ X, const float* __restrict__ Wr,
    const float* __restrict__ br, int* __restrict__ counts,
    float* __restrict__ wts, int* __restrict__ bucket) {
    const int lane = threadIdx.x;        // 0..63
    const int t0 = blockIdx.x * 8;       // 1024 blocks

    double acc[8][EXP];
#pragma unroll
    for (int t = 0; t < 8; ++t)
#pragma unroll
        for (int e = 0; e < EXP; ++e) acc[t][e] = 0.0;

    const float4* X4 = (const float4*)X;
    const float4* W4 = (const float4*)Wr;
#pragma unroll
    for (int i = 0; i < 8; ++i) {
        const int c = lane + 64 * i;  // float4 column, 0..511
        float4 xv[8];
#pragma unroll
        for (int t = 0; t < 8; ++t) xv[t] = X4[(size_t)(t0 + t) * 512 + c];
#pragma unroll
        for (int e = 0; e < EXP; ++e) {
            const float4 wv = W4[e * 512 + c];
#pragma unroll
            for (int t = 0; t < 8; ++t) {
                acc[t][e] += (double)xv[t].x * wv.x + (double)xv[t].y * wv.y +
                             (double)xv[t].z * wv.z + (double)xv[t].w * wv.w;
            }
        }
    }

    // full-wave butterfly reduce (all lanes end with the sum)
#pragma unroll
    for (int t = 0; t < 8; ++t)
#pragma unroll
        for (int e = 0; e < EXP; ++e) {
            double v = acc[t][e];
#pragma unroll
            for (int off = 32; off >= 1; off >>= 1) v += __shfl_xor(v, off, 64);
            acc[t][e] = v;
        }

#pragma unroll
    for (int t = 0; t < 8; ++t) {
        if (lane == t) {
            double lg[EXP];
#pragma unroll
            for (int e = 0; e < EXP; ++e) lg[e] = acc[t][e] + (double)br[e];
            double m = lg[0];
            int bi = 0;
#pragma unroll
            for (int e = 1; e < EXP; ++e)
                if (lg[e] > m) { m = lg[e]; bi = e; }
            float s = 0.f;
#pragma unroll
            for (int e = 0; e < EXP; ++e) s += __expf((float)(lg[e] - m));
            const int n = t0 + t;
            wts[n] = 1.0f / s;  // max softmax prob
            const int slot = atomicAdd(&counts[bi], 1);
            bucket[bi * NTOK + slot] = n;
        }
    }
}

// Grouped LoRA. R8 structure + register double-buffer prefetch: chunk ch+1's
// 16 float4 global loads are issued into the alternate register set while
// MFMA(ch) runs, doubling outstanding bytes per block (R6-vs-R8 showed the
// binder is outstanding-request concurrency, not bulk traffic). Accumulation
// order (ch asc, kk, m) bit-identical to R8.
__global__ __launch_bounds__(256, 2) void moe_lora_kernel(
    const float* __restrict__ X, const float* __restrict__ A,
    const float* __restrict__ B, const int* __restrict__ counts,
    const float* __restrict__ wts, const int* __restrict__ bucket,
    float* __restrict__ out) {
    const int e = blockIdx.x >> 7;       // MAXTILES == 128
    const int tile = blockIdx.x & 127;
    const int jbin = blockIdx.y;         // 0..JBINS-1, column half
    const int cnt = counts[e];
    const int base = tile * TTILE;
    if (base >= cnt) return;
    const int nt = min(TTILE, cnt - base);

    __shared__ int toks[TTILE];
    __shared__ float wt_s[TTILE];
    __shared__ short Xs[TTILE * BK];  // 64 rows x 128 bf16, swizzled, 16 KB
    __shared__ short As[RK * BK];     // 64 rows x 128 bf16, swizzled, 16 KB
    __shared__ short Hs[TTILE * RK];  // 64 x 64 bf16 h, XOR-swizzled, 8 KB

    const int tid = threadIdx.x;
    if (tid < TTILE) {
        const int tk = bucket[e * NTOK + base + min(tid, nt - 1)];
        toks[tid] = tk;
        wt_s[tid] = wts[tk];
    }
    __syncthreads();

    const int wv = tid >> 6;     // wave 0..3
    const int lane = tid & 63;
    const int lrow = lane & 15;  // M/N index within fragment
    const int lk = lane >> 4;    // k-block 0..3

    // ---- Step A: h[64][64] = Xtile @ A[e]^T, LDS-staged, reg-prefetched ----
    const float* Ae = A + (size_t)e * RK * DIM;
    const int scol = (tid & 31) * 4;   // f32 col within chunk (0..124)
    const int srow = tid >> 5;         // 0..7

    f32x4 hacc[MT];
#pragma unroll
    for (int m = 0; m < MT; ++m) hacc[m] = (f32x4){0.f, 0.f, 0.f, 0.f};

    float4 xrA[8], arA[8], xrB[8], arB[8];

#define ISSUE(XR, AR, CH)                                                      \
    {                                                                          \
        const int k0_ = (CH)*BK;                                               \
        _Pragma("unroll") for (int i = 0; i < 8; ++i) {                        \
            const int row = i * 8 + srow;                                      \
            XR[i] = *(const float4*)(X + (size_t)toks[row] * DIM + k0_ + scol);\
            AR[i] = *(const float4*)(Ae + (size_t)row * DIM + k0_ + scol);     \
        }                                                                      \
    }

#define STAGE(XR, AR)                                                          \
    {                                                                          \
        _Pragma("unroll") for (int i = 0; i < 8; ++i) {                        \
            const int row = i * 8 + srow;                                      \
            s16x4 hx = {f2bf(XR[i].x), f2bf(XR[i].y), f2bf(XR[i].z),           \
                        f2bf(XR[i].w)};                                        \
            *(s16x4*)((char*)Xs + ((row * 256 + scol * 2) ^ ((row & 7) << 4))) = hx; \
            s16x4 ha = {f2bf(AR[i].x), f2bf(AR[i].y), f2bf(AR[i].z),           \
                        f2bf(AR[i].w)};                                        \
            *(s16x4*)((char*)As + ((row * 256 + scol * 2) ^ ((row & 7) << 4))) = ha; \
        }                                                                      \
    }

#define MFMA_CHUNK()                                                           \
    {                                                                          \
        _Pragma("unroll") for (int kk = 0; kk < 4; ++kk) {                     \
            const int cb = kk * 64 + lk * 16;                                  \
            const int ar_ = wv * 16 + lrow;                                    \
            const bf16x8 af = *(const bf16x8*)((char*)As +                     \
                ((ar_ * 256 + cb) ^ ((ar_ & 7) << 4)));                        \
            _Pragma("unroll") for (int m = 0; m < MT; ++m) {                   \
                const int xr_ = m * 16 + lrow;                                 \
                const bf16x8 xf = *(const bf16x8*)((char*)Xs +                 \
                    ((xr_ * 256 + cb) ^ ((xr_ & 7) << 4)));                    \
                hacc[m] = __builtin_amdgcn_mfma_f32_16x16x32_bf16(             \
                    xf, af, hacc[m], 0, 0, 0);                                 \
            }                                                                  \
        }                                                                      \
    }

    ISSUE(xrA, arA, 0);
#pragma unroll 1
    for (int ch = 0; ch < DIM / BK; ch += 2) {
        __syncthreads();              // prior MFMA done with LDS
        STAGE(xrA, arA);
        ISSUE(xrB, arB, ch + 1);      // prefetch odd chunk
        __syncthreads();
        MFMA_CHUNK();                 // even chunk

        __syncthreads();
        STAGE(xrB, arB);
        if (ch + 2 < DIM / BK) ISSUE(xrA, arA, ch + 2);  // prefetch next even
        __syncthreads();
        MFMA_CHUNK();                 // odd chunk
    }
#undef ISSUE
#undef STAGE
#undef MFMA_CHUNK

    // write h to LDS as bf16, XOR-swizzled rows of 64 bf16 (128 B)
#pragma unroll
    for (int m = 0; m < MT; ++m) {
#pragma unroll
        for (int reg = 0; reg < 4; ++reg) {
            const int t = m * 16 + lk * 4 + reg;
            const int r = wv * 16 + lrow;
            const int byte = ((t * RK + r) * 2) ^ ((t & 7) << 4);
            *(short*)((char*)Hs + byte) = f2bf(hacc[m][reg]);
        }
    }
    __syncthreads();

    // ---- Step B: y[64][1024-chunk] = h @ B[e]^T, scale, scatter ----
    bf16x8 hf[MT][2];
#pragma unroll
    for (int m = 0; m < MT; ++m)
#pragma unroll
        for (int k2 = 0; k2 < 2; ++k2) {
            const int t = m * 16 + lrow;
            const int r = k2 * 32 + lk * 8;
            const int byte = ((t * RK + r) * 2) ^ ((t & 7) << 4);
            hf[m][k2] = *(const bf16x8*)((char*)Hs + byte);
        }

    float scl[MT][4];
    int trow[MT][4];
    bool tok_ok[MT][4];
#pragma unroll
    for (int m = 0; m < MT; ++m)
#pragma unroll
        for (int reg = 0; reg < 4; ++reg) {
            const int t = m * 16 + lk * 4 + reg;
            scl[m][reg] = SCALING * wt_s[t];
            trow[m][reg] = toks[t];
            tok_ok[m][reg] = (t < nt);
        }

    const float* Be = B + (size_t)e * OUTD * RK;
    const int j0 = jbin * (OUTD / 64 / JBINS);  // 16 j's per bin
    for (int j = j0; j < j0 + OUTD / 64 / JBINS; ++j) {
        const int n = (wv + 4 * j) * 16;
        f32x4 yacc[MT];
#pragma unroll
        for (int m = 0; m < MT; ++m) yacc[m] = (f32x4){0.f, 0.f, 0.f, 0.f};
#pragma unroll
        for (int k2 = 0; k2 < 2; ++k2) {
            const bf16x8 bf =
                load_cvt8(Be + (size_t)(n + lrow) * RK + k2 * 32 + lk * 8);
#pragma unroll
            for (int m = 0; m < MT; ++m)
                yacc[m] = __builtin_amdgcn_mfma_f32_16x16x32_bf16(hf[m][k2], bf, yacc[m], 0, 0, 0);
        }
#pragma unroll
        for (int m = 0; m < MT; ++m) {
#pragma unroll
            for (int reg = 0; reg < 4; ++reg) {
                if (tok_ok[m][reg]) {
                    const float y = yacc[m][reg] * scl[m][reg];
                    out[(size_t)trow[m][reg] * OUTD + n + lrow] = y;
                }
            }
        }
    }
}

extern "C" void kernel_launch(void* const* d_in, const int* in_sizes, int n_in,
                              void* d_out, int out_size, void* d_ws, size_t ws_size,
                              hipStream_t stream) {
    const float* X = (const float*)d_in[0];
    const float* A = (const float*)d_in[1];
    const float* B = (const float*)d_in[2];
    const float* Wr = (const float*)d_in[3];
    const float* br = (const float*)d_in[4];
    float* out = (float*)d_out;

    int* counts = (int*)d_ws;
    float* wts = (float*)((char*)d_ws + 64);
    int* bucket = (int*)((char*)d_ws + 64 + NTOK * 4);

    init_counts<<<1, 64, 0, stream>>>(counts);
    router_kernel<<<NTOK / 8, 64, 0, stream>>>(X, Wr, br, counts, wts, bucket);
    dim3 grid(EXP * MAXTILES, JBINS);
    moe_lora_kernel<<<grid, 256, 0, stream>>>(X, A, B, counts, wts, bucket, out);
}